// Round 1
// baseline (73.117 us; speedup 1.0000x reference)
//
#include <hip/hip_runtime.h>
#include <stdint.h>
#include <stddef.h>

#define NB 4
#define NC 320
#define NH 128
#define NW 240
#define ND 49
#define HW (NH * NW)          // 30720
#define CC 32                 // channels per chunk
#define NCHUNK (NC / CC)      // 10

typedef float f32x4 __attribute__((ext_vector_type(4)));
typedef short s16x8 __attribute__((ext_vector_type(8)));

__device__ __forceinline__ uint32_t bf16r(float f) {
  uint32_t u = __builtin_bit_cast(uint32_t, f);
  return (u + 0x7FFFu + ((u >> 16) & 1u)) >> 16;  // RNE f32 -> bf16 bits
}

// LDS column-block swizzle: spreads both the staging b128 writes (lane = w)
// and the fragment b128 reads (lane%16 = w) across all 32 banks.
__device__ __forceinline__ int swz(int w) { return (w ^ (w >> 2)) & 3; }

__global__ __launch_bounds__(256, 2) void cv_kernel(const float* __restrict__ X,
                                                    const float* __restrict__ Y,
                                                    float* __restrict__ O) {
  // [buf][arr][w][c] bf16, c-dim stored in XOR-swizzled 8-elem blocks.
  __shared__ short lds[2 * 2 * NW * CC];  // 30720 shorts = 61.44 KB

  const int tid = threadIdx.x;
  const int row = blockIdx.x;            // 0..511 = b*128 + h
  const int b = row >> 7, h = row & 127;
  const float* xrow = X + (size_t)b * NC * HW + (size_t)h * NW;
  const float* yrow = Y + (size_t)b * NC * HW + (size_t)h * NW;

  const int wave = tid >> 6;             // 0..3, owns wi-tiles wave, wave+4, wave+8, wave+12
  const int l = tid & 63;
  const int m = l & 15;                  // fragment row/col index
  const int q = l >> 4;                  // k-group (8 channels)

  f32x4 acc[4][4] = {};                  // [wi-slot][wj-slot]
  float sv[2][4][8];                     // staged chunk: [arr][c8][j]

  auto stage_load = [&](int chunk) {     // global -> regs (issue early)
    if (tid < NW) {
#pragma unroll
      for (int arr = 0; arr < 2; ++arr) {
        const float* src = arr ? yrow : xrow;
#pragma unroll
        for (int c8 = 0; c8 < 4; ++c8) {
          const float* p = src + (size_t)(chunk * CC + c8 * 8) * HW + tid;
#pragma unroll
          for (int j = 0; j < 8; ++j) sv[arr][c8][j] = p[(size_t)j * HW];
        }
      }
    }
  };

  auto stage_write = [&](int buf) {      // regs -> LDS bf16 (after compute)
    if (tid < NW) {
      const int w = tid, sw = swz(w);
#pragma unroll
      for (int arr = 0; arr < 2; ++arr) {
#pragma unroll
        for (int c8 = 0; c8 < 4; ++c8) {
          s16x8 s;
#pragma unroll
          for (int j = 0; j < 8; ++j) s[j] = (short)bf16r(sv[arr][c8][j]);
          *(s16x8*)&lds[((buf * 2 + arr) * NW + w) * CC + ((c8 ^ sw) * 8)] = s;
        }
      }
    }
  };

  auto compute = [&](int buf) {
#pragma unroll
    for (int i = 0; i < 4; ++i) {
      const int wt = wave + 4 * i;       // wi tile, 0..14
      if (wt <= 14) {
        const int wa = wt * 16 + m;
        const s16x8 a =
            *(const s16x8*)&lds[((buf * 2 + 0) * NW + wa) * CC + ((q ^ swz(wa)) * 8)];
#pragma unroll
        for (int ss = 0; ss < 4; ++ss) {
          const int st = wt - 3 + ss;    // wj tile in band [wt-3, wt]
          if (st >= 0) {
            const int wb = st * 16 + m;
            const s16x8 bb =
                *(const s16x8*)&lds[((buf * 2 + 1) * NW + wb) * CC + ((q ^ swz(wb)) * 8)];
            acc[i][ss] = __builtin_amdgcn_mfma_f32_16x16x32_bf16(a, bb, acc[i][ss], 0, 0, 0);
          }
        }
      }
    }
  };

  // Prologue: stage chunk 0 into buf 0
  stage_load(0);
  stage_write(0);
  __syncthreads();

  for (int k = 0; k < NCHUNK; ++k) {
    if (k + 1 < NCHUNK) stage_load(k + 1);     // HBM latency hides under MFMA
    compute(k & 1);
    if (k + 1 < NCHUNK) stage_write((k + 1) & 1);
    __syncthreads();
  }

  // Epilogue: out[d][b][h][w], d = wi - wj. Virtual tiles (st < 0) emit the
  // w < d zero region, so every output element is written exactly once.
  float* orow = O + ((size_t)b * NH + h) * NW;
#pragma unroll
  for (int i = 0; i < 4; ++i) {
    const int wt = wave + 4 * i;
    if (wt > 14) continue;
#pragma unroll
    for (int ss = 0; ss < 4; ++ss) {
      const int st = wt - 3 + ss;
      const int wj = st * 16 + m;
#pragma unroll
      for (int r = 0; r < 4; ++r) {
        const int wi = wt * 16 + q * 4 + r;    // C/D: row = (lane>>4)*4 + reg (m89)
        const int d = wi - wj;
        if (d >= 0 && d < ND) {
          const float v = (st >= 0) ? acc[i][ss][r] : 0.0f;
          orow[(size_t)d * (NB * HW) + wi] = v;
        }
      }
    }
  }
}

extern "C" void kernel_launch(void* const* d_in, const int* in_sizes, int n_in,
                              void* d_out, int out_size, void* d_ws, size_t ws_size,
                              hipStream_t stream) {
  const float* x = (const float*)d_in[0];
  const float* y = (const float*)d_in[1];
  float* out = (float*)d_out;
  cv_kernel<<<dim3(512), dim3(256), 0, stream>>>(x, y, out);
}